// Round 2
// baseline (1305.162 us; speedup 1.0000x reference)
//
#include <hip/hip_runtime.h>
#include <math.h>

#define NN 48
#define MD 56

__device__ __forceinline__ float rcp_f(float x){
#if __has_builtin(__builtin_amdgcn_rcpf)
  return __builtin_amdgcn_rcpf(x);
#else
  return 1.0f/x;
#endif
}

// padded row offset for the 48x64 h-tile: +4 floats every 4 rows.
// Broadcast column reads: <=2-way bank aliasing (free per m136). 16B alignment kept.
#define HROW(r) ((r)*64 + (((r)>>2)<<2))

// One block per batch item; 256 threads.
// LDS 26528 B -> 6 blocks/CU (24 waves). All transcendentals PRECISE (tanhf/expf/div):
// the first-softmax argmax feeds mask_second; fast-math perturbation flips near-ties
// and breaks correctness (verified R1 failure). Matmul chains bit-identical to the
// 776us passing kernel.
__global__ __launch_bounds__(256, 6)
void policy_fwd(const int* __restrict__ Nmat, const float* __restrict__ adj,
                const float* __restrict__ W1, const float* __restrict__ b1,
                const float* __restrict__ W2, const float* __restrict__ b2,
                const float* __restrict__ agg_sW, const float* __restrict__ agg_sb,
                const float* __restrict__ agg_tW, const float* __restrict__ agg_tb,
                const float* __restrict__ l1W, const float* __restrict__ l1b,
                const float* __restrict__ l2W, const float* __restrict__ l2b,
                const float* __restrict__ f1, const float* __restrict__ f2,
                const float* __restrict__ s1, const float* __restrict__ s2,
                const float* __restrict__ e1, const float* __restrict__ e2,
                const float* __restrict__ t1W, const float* __restrict__ t1b,
                const float* __restrict__ t2W, const float* __restrict__ t2b,
                const float* __restrict__ v1W, const float* __restrict__ v1b,
                const float* __restrict__ v2W, const float* __restrict__ v2b,
                const float* __restrict__ v3W, const float* __restrict__ v3b,
                float* __restrict__ out)
{
  __shared__ __align__(16) float sA[2304];   // A stride 48; after M3: ch1 partials [0..1024)
  __shared__ __align__(16) float sHB[3120];  // deg[0..144) pre-A; h/h2/h_out HROW tile; tail sT
  __shared__ __align__(16) float sEP[1152];  // embT 9x128; after M4: ch0 partials[16][64] + gsum[128]
  __shared__ int   sNi[MD];                  // N values pre-multiplied by 128

  const int b   = blockIdx.x;
  const int tid = threadIdx.x;
  const float* adjB = adj + (size_t)b * (3*NN*NN);
  float* sDeg = sHB;   // deg region dead before h rows are written

  if (tid < MD) sNi[tid] = Nmat[b*MD + tid] * 128;

  // ---- degrees: deg[r*48+i] = 1/(1+row_sum); 16 lanes per row (exact div) ----
  {
    const int lane = tid & 15, grp = tid >> 4;
    for (int p = 0; p < 9; ++p) {
      const int row = p*16 + grp;               // r*48+i
      const float* rp = adjB + row*NN;
      float s = rp[lane] + rp[lane+16] + rp[lane+32];
      s += __shfl_down(s, 8, 16);
      s += __shfl_down(s, 4, 16);
      s += __shfl_down(s, 2, 16);
      s += __shfl_down(s, 1, 16);
      if (lane == 0) sDeg[row] = 1.0f/(s + 1.0f);
    }
  }
  // embT[t][d] = W1[t][d] + b1[d]  (9x128)
  for (int o = tid; o < 1152; o += 256) sEP[o] = W1[o] + b1[o & 127];
  __syncthreads();

  // ---- A[i][j] = sum_r adj[r][i][j]*deg[r][i] (stride-1 writes) ----
  for (int o = tid; o < NN*NN; o += 256) {
    const int i = o / NN, j = o - i*NN;
    const float v = adjB[i*NN + j]          * sDeg[i]
                  + adjB[(NN + i)*NN + j]   * sDeg[NN + i]
                  + adjB[(2*NN + i)*NN + j] * sDeg[2*NN + i];
    sA[i*48 + j] = v;
  }
  __syncthreads();   // sA ready; deg region dead

  const int i2 = (tid >> 4)*3, d2 = (tid & 15)*4;
  float* hr[3] = { &sHB[HROW(i2)], &sHB[HROW(i2+1)], &sHB[HROW(i2+2)] };

  // ---- M1+M2 fused in two 64-column rounds (chains identical to unfused) ----
  float acc2[3][4] = {};
  #pragma unroll
  for (int r = 0; r < 2; ++r) {
    const int dg = r*64 + d2;   // global d in [0,128)
    // M1: h(i2..i2+2, dg..dg+3)
    {
      float acc[3][4] = {};
      #pragma unroll 4
      for (int k = 0; k < NN; ++k) {
        const int nk = sNi[k];                  // already *128
        const float4 bv = *(const float4*)&sEP[nk + dg];
        const float* ap = &sA[i2*48 + k];
        #pragma unroll
        for (int ii = 0; ii < 3; ++ii) {
          const float a = ap[ii*48];
          acc[ii][0] = fmaf(a, bv.x, acc[ii][0]);
          acc[ii][1] = fmaf(a, bv.y, acc[ii][1]);
          acc[ii][2] = fmaf(a, bv.z, acc[ii][2]);
          acc[ii][3] = fmaf(a, bv.w, acc[ii][3]);
        }
      }
      #pragma unroll
      for (int ii = 0; ii < 3; ++ii) {
        const float4 rv = *(const float4*)&sEP[sNi[i2+ii] + dg];
        float4 o;
        o.x = tanhf(acc[ii][0] + rv.x);
        o.y = tanhf(acc[ii][1] + rv.y);
        o.z = tanhf(acc[ii][2] + rv.z);
        o.w = tanhf(acc[ii][3] + rv.w);
        *(float4*)&hr[ii][d2] = o;
      }
    }
    __syncthreads();   // h block visible
    // M2 accumulate: h2 += h[:,blk] @ W2[blk,:]
    {
      const float* W2r = W2 + (size_t)r*64*64;
      #pragma unroll 8
      for (int k = 0; k < 64; ++k) {
        const float4 bv = *(const float4*)&W2r[k*64 + d2];
        #pragma unroll
        for (int ii = 0; ii < 3; ++ii) {
          const float a = hr[ii][k];
          acc2[ii][0] = fmaf(a, bv.x, acc2[ii][0]);
          acc2[ii][1] = fmaf(a, bv.y, acc2[ii][1]);
          acc2[ii][2] = fmaf(a, bv.z, acc2[ii][2]);
          acc2[ii][3] = fmaf(a, bv.w, acc2[ii][3]);
        }
      }
    }
    __syncthreads();   // all reads of h block done before overwrite
  }
  // h2 = acc2 + b2 -> same tile (h dead)
  {
    const float4 bb = *(const float4*)&b2[d2];
    #pragma unroll
    for (int ii = 0; ii < 3; ++ii) {
      float4 o;
      o.x = acc2[ii][0] + bb.x; o.y = acc2[ii][1] + bb.y;
      o.z = acc2[ii][2] + bb.z; o.w = acc2[ii][3] + bb.w;
      *(float4*)&hr[ii][d2] = o;
    }
  }
  __syncthreads();

  // ---- M3: h_out = tanh(A@h2 + h2) computed into regs, then written IN PLACE ----
  {
    float acc[3][4] = {};
    #pragma unroll 4
    for (int k = 0; k < NN; ++k) {
      const float4 bv = *(const float4*)&sHB[HROW(k) + d2];
      const float* ap = &sA[i2*48 + k];
      #pragma unroll
      for (int ii = 0; ii < 3; ++ii) {
        const float a = ap[ii*48];
        acc[ii][0] = fmaf(a, bv.x, acc[ii][0]);
        acc[ii][1] = fmaf(a, bv.y, acc[ii][1]);
        acc[ii][2] = fmaf(a, bv.z, acc[ii][2]);
        acc[ii][3] = fmaf(a, bv.w, acc[ii][3]);
      }
    }
    float4 rv[3];
    #pragma unroll
    for (int ii = 0; ii < 3; ++ii) rv[ii] = *(const float4*)&hr[ii][d2];
    __syncthreads();   // every thread finished reading h2
    #pragma unroll
    for (int ii = 0; ii < 3; ++ii) {
      float4 o;
      o.x = tanhf(acc[ii][0] + rv[ii].x);
      o.y = tanhf(acc[ii][1] + rv[ii].y);
      o.z = tanhf(acc[ii][2] + rv[ii].z);
      o.w = tanhf(acc[ii][3] + rv[ii].w);
      *(float4*)&hr[ii][d2] = o;
    }
  }
  __syncthreads();   // h_out visible; sA (A) dead; sEP (emb) dead

  // ---- M4: both channels in ONE k-pass (chains identical) ----
  {
    float as0[3][4] = {}, as1[3][4] = {}, at0[3][4] = {}, at1[3][4] = {};
    #pragma unroll 4
    for (int k = 0; k < 64; ++k) {
      const float4 bs0 = *(const float4*)&agg_sW[k*128 + d2];
      const float4 bs1 = *(const float4*)&agg_sW[k*128 + 64 + d2];
      const float4 bt0 = *(const float4*)&agg_tW[k*128 + d2];
      const float4 bt1 = *(const float4*)&agg_tW[k*128 + 64 + d2];
      #pragma unroll
      for (int ii = 0; ii < 3; ++ii) {
        const float a = hr[ii][k];
        as0[ii][0] = fmaf(a, bs0.x, as0[ii][0]);
        as0[ii][1] = fmaf(a, bs0.y, as0[ii][1]);
        as0[ii][2] = fmaf(a, bs0.z, as0[ii][2]);
        as0[ii][3] = fmaf(a, bs0.w, as0[ii][3]);
        as1[ii][0] = fmaf(a, bs1.x, as1[ii][0]);
        as1[ii][1] = fmaf(a, bs1.y, as1[ii][1]);
        as1[ii][2] = fmaf(a, bs1.z, as1[ii][2]);
        as1[ii][3] = fmaf(a, bs1.w, as1[ii][3]);
        at0[ii][0] = fmaf(a, bt0.x, at0[ii][0]);
        at0[ii][1] = fmaf(a, bt0.y, at0[ii][1]);
        at0[ii][2] = fmaf(a, bt0.z, at0[ii][2]);
        at0[ii][3] = fmaf(a, bt0.w, at0[ii][3]);
        at1[ii][0] = fmaf(a, bt1.x, at1[ii][0]);
        at1[ii][1] = fmaf(a, bt1.y, at1[ii][1]);
        at1[ii][2] = fmaf(a, bt1.z, at1[ii][2]);
        at1[ii][3] = fmaf(a, bt1.w, at1[ii][3]);
      }
    }
    // epilogue: onehot-gather rows + biases from global (L2-hot); add order: acc + gather + bias
    float p0[4] = {0.f,0.f,0.f,0.f}, p1[4] = {0.f,0.f,0.f,0.f};
    const float4 bsb0 = *(const float4*)&agg_sb[d2];
    const float4 bsb1 = *(const float4*)&agg_sb[64 + d2];
    const float4 btb0 = *(const float4*)&agg_tb[d2];
    const float4 btb1 = *(const float4*)&agg_tb[64 + d2];
    const float bsb0a[4] = {bsb0.x,bsb0.y,bsb0.z,bsb0.w};
    const float bsb1a[4] = {bsb1.x,bsb1.y,bsb1.z,bsb1.w};
    const float btb0a[4] = {btb0.x,btb0.y,btb0.z,btb0.w};
    const float btb1a[4] = {btb1.x,btb1.y,btb1.z,btb1.w};
    #pragma unroll
    for (int ii = 0; ii < 3; ++ii) {
      const int t = sNi[i2+ii];                // already *128
      const float* gs = agg_sW + 64*128 + t;
      const float* gt = agg_tW + 64*128 + t;
      #pragma unroll
      for (int dd = 0; dd < 4; ++dd) {
        const float sg0 = 1.0f/(1.0f + expf(-(as0[ii][dd] + gs[d2+dd]    + bsb0a[dd])));
        const float tg0 = tanhf(at0[ii][dd] + gt[d2+dd]    + btb0a[dd]);
        p0[dd] = fmaf(sg0, tg0, p0[dd]);
        const float sg1 = 1.0f/(1.0f + expf(-(as1[ii][dd] + gs[64+d2+dd] + bsb1a[dd])));
        const float tg1 = tanhf(at1[ii][dd] + gt[64+d2+dd] + btb1a[dd]);
        p1[dd] = fmaf(sg1, tg1, p1[dd]);
      }
    }
    const int grp = tid >> 4;
    *(float4*)&sEP[grp*64 + d2] = *(float4*)p0;   // ch0 partials (emb dead)
    *(float4*)&sA [grp*64 + d2] = *(float4*)p1;   // ch1 partials (A dead)
  }
  __syncthreads();
  if (tid < 64) {                      // fixed-order 16-group sums
    float s = 0.0f;
    #pragma unroll
    for (int g = 0; g < 16; ++g) s += sEP[g*64 + tid];
    sEP[1024 + tid] = s;               // gsum ch0
  } else if (tid < 128) {
    const int m = tid - 64;
    float s = 0.0f;
    #pragma unroll
    for (int g = 0; g < 16; ++g) s += sA[g*64 + m];
    sEP[1024 + 64 + m] = s;            // gsum ch1
  }
  __syncthreads();

  // ---- tail MLP; sT lives in sHB (h_out dead after M4) ----
  float* sT = sHB;
  const float* sGsum = &sEP[1024];
  if (tid < 128) sT[tid + 1024] = tanhf(sGsum[tid]);   // g: sT[1024..1152)
  __syncthreads();
  if (tid < 128) {                                     // a1: sT[1152..1280)
    float a = l1b[tid];
    for (int k = 0; k < 128; ++k) a = fmaf(sT[1024+k], l1W[k*128 + tid], a);
    sT[1152 + tid] = a;
  }
  __syncthreads();
  if (tid < 64) {                                      // hfeat: sT[1280..1344)
    float a = l2b[tid];
    for (int k = 0; k < 128; ++k) a = fmaf(sT[1152+k], l2W[k*64 + tid], a);
    sT[1280 + tid] = a;
  }
  __syncthreads();
  if (tid < 160) {                                     // 5 heads L1: sT[1344..1504)
    const int hh = tid >> 5, j = tid & 31;
    const float* Wp = (hh==0) ? f1 : (hh==1) ? s1 : (hh==2) ? e1 : (hh==3) ? t1W : v1W;
    float a = (hh==3) ? t1b[j] : (hh==4) ? v1b[j] : 0.0f;
    for (int k = 0; k < 64; ++k) a = fmaf(sT[1280+k], Wp[k*32 + j], a);
    sT[1344 + tid] = (a > 0.0f) ? a : 0.1f*a;
  }
  __syncthreads();
  if (tid < 56) {                                      // out1: sT[1504..1560)
    float a = 0.0f;
    for (int k = 0; k < 32; ++k) a = fmaf(sT[1344+k], f2[k*56 + tid], a);
    sT[1504 + tid] = a;
  } else if (tid < 112) {                              // out2: sT[1560..1616)
    const int m = tid - 56; float a = 0.0f;
    for (int k = 0; k < 32; ++k) a = fmaf(sT[1376+k], s2[k*56 + m], a);
    sT[1560 + m] = a;
  } else if (tid < 115) {                              // oute: sT[1616..1619)
    const int m = tid - 112; float a = 0.0f;
    for (int k = 0; k < 32; ++k) a = fmaf(sT[1408+k], e2[k*3 + m], a);
    sT[1616 + m] = a;
  } else if (tid < 117) {                              // outs: sT[1619..1621)
    const int m = tid - 115; float a = t2b[m];
    for (int k = 0; k < 32; ++k) a = fmaf(sT[1440+k], t2W[k*2 + m], a);
    sT[1619 + m] = a;
  } else if (tid < 133) {                              // v2h: sT[1624..1640)
    const int m = tid - 117; float a = v2b[m];
    for (int k = 0; k < 32; ++k) a = fmaf(sT[1472+k], v2W[k*16 + m], a);
    sT[1624 + m] = (a > 0.0f) ? a : 0.1f*a;
  }
  __syncthreads();
  if (tid == 0) {                                      // value: sT[1640]
    float a = v3b[0];
    for (int k = 0; k < 16; ++k) a = fmaf(sT[1624+k], v3W[k], a);
    sT[1640] = a;
  }
  __syncthreads();

  // ---- masks + softmaxes, wave 0 (post-argmax: fast math OK, passed before) ----
  if (tid < 64) {
    const int m = tid;
    const bool inb = (m < MD);
    const bool ex  = inb && (sNi[m] > 0) && (m < NN);
    const size_t ob = (size_t)b * 118;

    float lg1 = inb ? (sT[1504+m] + (ex ? 0.0f : -10000.0f)) : -INFINITY;
    float mv = lg1; int mi = inb ? m : 1000;
    #pragma unroll
    for (int off = 32; off > 0; off >>= 1) {
      const float ov = __shfl_down(mv, off);
      const int   oi = __shfl_down(mi, off);
      if (ov > mv || (ov == mv && oi < mi)) { mv = ov; mi = oi; }
    }
    mv = __shfl(mv, 0);
    const int first = __shfl(mi, 0);
    float ev = inb ? __expf(lg1 - mv) : 0.0f;
    float sum1 = ev;
    #pragma unroll
    for (int off = 32; off > 0; off >>= 1) sum1 += __shfl_down(sum1, off);
    sum1 = rcp_f(__shfl(sum1, 0));
    if (inb) out[ob + m] = ev * sum1;

    const bool m2 = inb && ((ex || m >= NN) && (m != first));
    float lg2 = inb ? (sT[1560+m] + (m2 ? 0.0f : -10000.0f)) : -INFINITY;
    float mv2 = lg2;
    #pragma unroll
    for (int off = 32; off > 0; off >>= 1) mv2 = fmaxf(mv2, __shfl_down(mv2, off));
    mv2 = __shfl(mv2, 0);
    float ev2 = inb ? __expf(lg2 - mv2) : 0.0f;
    float sum2 = ev2;
    #pragma unroll
    for (int off = 32; off > 0; off >>= 1) sum2 += __shfl_down(sum2, off);
    sum2 = rcp_f(__shfl(sum2, 0));
    if (inb) out[ob + 56 + m] = ev2 * sum2;

    if (m < 3) {
      const float x0 = sT[1616], x1 = sT[1617], x2 = sT[1618];
      const float mx = fmaxf(x0, fmaxf(x1, x2));
      const float q0 = __expf(x0-mx), q1 = __expf(x1-mx), q2 = __expf(x2-mx);
      out[ob + 112 + m] = ((m==0) ? q0 : (m==1) ? q1 : q2) / (q0+q1+q2);
    }
    if (m < 2) {
      const float x0 = sT[1619], x1 = sT[1620];
      const float mx = fmaxf(x0, x1);
      const float q0 = __expf(x0-mx), q1 = __expf(x1-mx);
      out[ob + 115 + m] = ((m==0) ? q0 : q1) / (q0+q1);
    }
    if (m == 0) out[ob + 117] = sT[1640];
  }
}

extern "C" void kernel_launch(void* const* d_in, const int* in_sizes, int n_in,
                              void* d_out, int out_size, void* d_ws, size_t ws_size,
                              hipStream_t stream) {
  (void)n_in; (void)out_size; (void)d_ws; (void)ws_size;
  const int B = in_sizes[0] / MD;
  policy_fwd<<<dim3(B), dim3(256), 0, stream>>>(
      (const int*)d_in[0],  (const float*)d_in[1],
      (const float*)d_in[2],  (const float*)d_in[3],
      (const float*)d_in[4],  (const float*)d_in[5],
      (const float*)d_in[6],  (const float*)d_in[7],
      (const float*)d_in[8],  (const float*)d_in[9],
      (const float*)d_in[10], (const float*)d_in[11],
      (const float*)d_in[12], (const float*)d_in[13],
      (const float*)d_in[14], (const float*)d_in[15],
      (const float*)d_in[16], (const float*)d_in[17],
      (const float*)d_in[18], (const float*)d_in[19],
      (const float*)d_in[20], (const float*)d_in[21],
      (const float*)d_in[22], (const float*)d_in[23],
      (const float*)d_in[24], (const float*)d_in[25],
      (const float*)d_in[26], (const float*)d_in[27],
      (const float*)d_in[28], (const float*)d_in[29],
      (float*)d_out);
}

// Round 3
// 900.838 us; speedup vs baseline: 1.4488x; 1.4488x over previous
//
#include <hip/hip_runtime.h>
#include <math.h>

#define NN 48
#define MD 56

__device__ __forceinline__ float rcp_f(float x){
#if __has_builtin(__builtin_amdgcn_rcpf)
  return __builtin_amdgcn_rcpf(x);
#else
  return 1.0f/x;
#endif
}

// One block per batch item; 256 threads.
// LDS: sA 9216 + sHB 13056 + sEP 4608 + sNi 224 = 27104 B (~27136 alloc) -> 6 blocks/CU
// if VGPR<=64. launch_bounds(256,4): proven no-spill allocator regime (R2's (256,6)
// forced 40 VGPR + 500MB scratch spills -> 1100us). M4 split into two column-half
// passes to cut peak acc pressure 48->24 regs (chains bit-identical). h tile stride 68:
// conflict-free broadcast column reads (rows +3 apart -> banks {0,12,24,4}).
// All transcendentals PRECISE (tanhf/expf/div): first-softmax argmax feeds mask_second;
// fast-math flips near-ties (verified R1 failure).
__global__ __launch_bounds__(256, 4)
void policy_fwd(const int* __restrict__ Nmat, const float* __restrict__ adj,
                const float* __restrict__ W1, const float* __restrict__ b1,
                const float* __restrict__ W2, const float* __restrict__ b2,
                const float* __restrict__ agg_sW, const float* __restrict__ agg_sb,
                const float* __restrict__ agg_tW, const float* __restrict__ agg_tb,
                const float* __restrict__ l1W, const float* __restrict__ l1b,
                const float* __restrict__ l2W, const float* __restrict__ l2b,
                const float* __restrict__ f1, const float* __restrict__ f2,
                const float* __restrict__ s1, const float* __restrict__ s2,
                const float* __restrict__ e1, const float* __restrict__ e2,
                const float* __restrict__ t1W, const float* __restrict__ t1b,
                const float* __restrict__ t2W, const float* __restrict__ t2b,
                const float* __restrict__ v1W, const float* __restrict__ v1b,
                const float* __restrict__ v2W, const float* __restrict__ v2b,
                const float* __restrict__ v3W, const float* __restrict__ v3b,
                float* __restrict__ out)
{
  __shared__ __align__(16) float sA[2304];   // A stride 48; after M3: ch1 partials [0..1024)
  __shared__ __align__(16) float sHB[3264];  // h/h2/h_out 48x68; deg [3104..3248); tail sT [1024..1641)
  __shared__ __align__(16) float sEP[1152];  // embT 9x128; after M1: ch0 partials [0..1024) + gsum [1024..1152)
  __shared__ int   sNi[MD];                  // N values pre-multiplied by 128

  const int b   = blockIdx.x;
  const int tid = threadIdx.x;
  const float* adjB = adj + (size_t)b * (3*NN*NN);
  float* sDeg = &sHB[3104];

  if (tid < MD) sNi[tid] = Nmat[b*MD + tid] * 128;

  // ---- degrees: deg[r*48+i] = 1/(1+row_sum); 16 lanes per row (exact div) ----
  {
    const int lane = tid & 15, grp = tid >> 4;
    for (int p = 0; p < 9; ++p) {
      const int row = p*16 + grp;               // r*48+i
      const float* rp = adjB + row*NN;
      float s = rp[lane] + rp[lane+16] + rp[lane+32];
      s += __shfl_down(s, 8, 16);
      s += __shfl_down(s, 4, 16);
      s += __shfl_down(s, 2, 16);
      s += __shfl_down(s, 1, 16);
      if (lane == 0) sDeg[row] = 1.0f/(s + 1.0f);
    }
  }
  // embT[t][d] = W1[t][d] + b1[d]  (9x128)
  for (int o = tid; o < 1152; o += 256) sEP[o] = W1[o] + b1[o & 127];
  __syncthreads();

  // ---- A[i][j] = sum_r adj[r][i][j]*deg[r][i] (stride-1 writes) ----
  for (int o = tid; o < NN*NN; o += 256) {
    const int i = o / NN, j = o - i*NN;
    const float v = adjB[i*NN + j]          * sDeg[i]
                  + adjB[(NN + i)*NN + j]   * sDeg[NN + i]
                  + adjB[(2*NN + i)*NN + j] * sDeg[2*NN + i];
    sA[i*48 + j] = v;
  }
  __syncthreads();   // sA ready; deg region dead

  const int i2 = (tid >> 4)*3, d2 = (tid & 15)*4;

  // ---- M1+M2 fused in two 64-column rounds (chains identical to unfused) ----
  float acc2[3][4] = {};
  #pragma unroll
  for (int r = 0; r < 2; ++r) {
    const int dg = r*64 + d2;   // global d in [0,128)
    // M1: h(i2..i2+2, dg..dg+3)
    {
      float acc[3][4] = {};
      #pragma unroll 4
      for (int k = 0; k < NN; ++k) {
        const int nk = sNi[k];                  // already *128
        const float4 bv = *(const float4*)&sEP[nk + dg];
        const float* ap = &sA[i2*48 + k];
        #pragma unroll
        for (int ii = 0; ii < 3; ++ii) {
          const float a = ap[ii*48];
          acc[ii][0] = fmaf(a, bv.x, acc[ii][0]);
          acc[ii][1] = fmaf(a, bv.y, acc[ii][1]);
          acc[ii][2] = fmaf(a, bv.z, acc[ii][2]);
          acc[ii][3] = fmaf(a, bv.w, acc[ii][3]);
        }
      }
      #pragma unroll
      for (int ii = 0; ii < 3; ++ii) {
        const float4 rv = *(const float4*)&sEP[sNi[i2+ii] + dg];
        float4 o;
        o.x = tanhf(acc[ii][0] + rv.x);
        o.y = tanhf(acc[ii][1] + rv.y);
        o.z = tanhf(acc[ii][2] + rv.z);
        o.w = tanhf(acc[ii][3] + rv.w);
        *(float4*)&sHB[(i2+ii)*68 + d2] = o;
      }
    }
    __syncthreads();   // h block visible
    // M2 accumulate: h2 += h[:,blk] @ W2[blk,:]
    {
      const float* W2r = W2 + (size_t)r*64*64;
      #pragma unroll 8
      for (int k = 0; k < 64; ++k) {
        const float4 bv = *(const float4*)&W2r[k*64 + d2];
        const float* ap = &sHB[i2*68 + k];
        #pragma unroll
        for (int ii = 0; ii < 3; ++ii) {
          const float a = ap[ii*68];
          acc2[ii][0] = fmaf(a, bv.x, acc2[ii][0]);
          acc2[ii][1] = fmaf(a, bv.y, acc2[ii][1]);
          acc2[ii][2] = fmaf(a, bv.z, acc2[ii][2]);
          acc2[ii][3] = fmaf(a, bv.w, acc2[ii][3]);
        }
      }
    }
    __syncthreads();   // all reads of h block done before overwrite
  }
  // h2 = acc2 + b2 -> same tile (h dead); keep h2 values in regs for the M3 residual
  float h2v[3][4];
  {
    const float4 bb = *(const float4*)&b2[d2];
    #pragma unroll
    for (int ii = 0; ii < 3; ++ii) {
      h2v[ii][0] = acc2[ii][0] + bb.x; h2v[ii][1] = acc2[ii][1] + bb.y;
      h2v[ii][2] = acc2[ii][2] + bb.z; h2v[ii][3] = acc2[ii][3] + bb.w;
      float4 o; o.x = h2v[ii][0]; o.y = h2v[ii][1]; o.z = h2v[ii][2]; o.w = h2v[ii][3];
      *(float4*)&sHB[(i2+ii)*68 + d2] = o;
    }
  }
  __syncthreads();

  // ---- M3: h_out = tanh(A@h2 + h2); residual from regs; in-place write after barrier ----
  {
    float acc[3][4] = {};
    #pragma unroll 4
    for (int k = 0; k < NN; ++k) {
      const float4 bv = *(const float4*)&sHB[k*68 + d2];
      const float* ap = &sA[i2*48 + k];
      #pragma unroll
      for (int ii = 0; ii < 3; ++ii) {
        const float a = ap[ii*48];
        acc[ii][0] = fmaf(a, bv.x, acc[ii][0]);
        acc[ii][1] = fmaf(a, bv.y, acc[ii][1]);
        acc[ii][2] = fmaf(a, bv.z, acc[ii][2]);
        acc[ii][3] = fmaf(a, bv.w, acc[ii][3]);
      }
    }
    __syncthreads();   // every thread finished reading h2
    #pragma unroll
    for (int ii = 0; ii < 3; ++ii) {
      float4 o;
      o.x = tanhf(acc[ii][0] + h2v[ii][0]);
      o.y = tanhf(acc[ii][1] + h2v[ii][1]);
      o.z = tanhf(acc[ii][2] + h2v[ii][2]);
      o.w = tanhf(acc[ii][3] + h2v[ii][3]);
      *(float4*)&sHB[(i2+ii)*68 + d2] = o;
    }
  }
  __syncthreads();   // h_out visible; sA (A) dead; sEP (emb) dead

  // ---- M4 pass 0: columns 0..63 of both channels (24 accs) ----
  {
    float as0[3][4] = {}, at0[3][4] = {};
    #pragma unroll 4
    for (int k = 0; k < 64; ++k) {
      const float4 bs0 = *(const float4*)&agg_sW[k*128 + d2];
      const float4 bt0 = *(const float4*)&agg_tW[k*128 + d2];
      const float* ap = &sHB[i2*68 + k];
      #pragma unroll
      for (int ii = 0; ii < 3; ++ii) {
        const float a = ap[ii*68];
        as0[ii][0] = fmaf(a, bs0.x, as0[ii][0]);
        as0[ii][1] = fmaf(a, bs0.y, as0[ii][1]);
        as0[ii][2] = fmaf(a, bs0.z, as0[ii][2]);
        as0[ii][3] = fmaf(a, bs0.w, as0[ii][3]);
        at0[ii][0] = fmaf(a, bt0.x, at0[ii][0]);
        at0[ii][1] = fmaf(a, bt0.y, at0[ii][1]);
        at0[ii][2] = fmaf(a, bt0.z, at0[ii][2]);
        at0[ii][3] = fmaf(a, bt0.w, at0[ii][3]);
      }
    }
    float p0[4] = {0.f,0.f,0.f,0.f};
    const float4 bsb0 = *(const float4*)&agg_sb[d2];
    const float4 btb0 = *(const float4*)&agg_tb[d2];
    const float bsb0a[4] = {bsb0.x,bsb0.y,bsb0.z,bsb0.w};
    const float btb0a[4] = {btb0.x,btb0.y,btb0.z,btb0.w};
    #pragma unroll
    for (int ii = 0; ii < 3; ++ii) {
      const int t = sNi[i2+ii];                // already *128
      const float* gs = agg_sW + 64*128 + t;
      const float* gt = agg_tW + 64*128 + t;
      #pragma unroll
      for (int dd = 0; dd < 4; ++dd) {
        const float sg0 = 1.0f/(1.0f + expf(-(as0[ii][dd] + gs[d2+dd] + bsb0a[dd])));
        const float tg0 = tanhf(at0[ii][dd] + gt[d2+dd] + btb0a[dd]);
        p0[dd] = fmaf(sg0, tg0, p0[dd]);
      }
    }
    const int grp = tid >> 4;
    *(float4*)&sEP[grp*64 + d2] = *(float4*)p0;   // ch0 partials (emb dead)
  }
  // ---- M4 pass 1: columns 64..127 (24 accs) ----
  {
    float as1[3][4] = {}, at1[3][4] = {};
    #pragma unroll 4
    for (int k = 0; k < 64; ++k) {
      const float4 bs1 = *(const float4*)&agg_sW[k*128 + 64 + d2];
      const float4 bt1 = *(const float4*)&agg_tW[k*128 + 64 + d2];
      const float* ap = &sHB[i2*68 + k];
      #pragma unroll
      for (int ii = 0; ii < 3; ++ii) {
        const float a = ap[ii*68];
        as1[ii][0] = fmaf(a, bs1.x, as1[ii][0]);
        as1[ii][1] = fmaf(a, bs1.y, as1[ii][1]);
        as1[ii][2] = fmaf(a, bs1.z, as1[ii][2]);
        as1[ii][3] = fmaf(a, bs1.w, as1[ii][3]);
        at1[ii][0] = fmaf(a, bt1.x, at1[ii][0]);
        at1[ii][1] = fmaf(a, bt1.y, at1[ii][1]);
        at1[ii][2] = fmaf(a, bt1.z, at1[ii][2]);
        at1[ii][3] = fmaf(a, bt1.w, at1[ii][3]);
      }
    }
    float p1[4] = {0.f,0.f,0.f,0.f};
    const float4 bsb1 = *(const float4*)&agg_sb[64 + d2];
    const float4 btb1 = *(const float4*)&agg_tb[64 + d2];
    const float bsb1a[4] = {bsb1.x,bsb1.y,bsb1.z,bsb1.w};
    const float btb1a[4] = {btb1.x,btb1.y,btb1.z,btb1.w};
    #pragma unroll
    for (int ii = 0; ii < 3; ++ii) {
      const int t = sNi[i2+ii];                // already *128
      const float* gs = agg_sW + 64*128 + t;
      const float* gt = agg_tW + 64*128 + t;
      #pragma unroll
      for (int dd = 0; dd < 4; ++dd) {
        const float sg1 = 1.0f/(1.0f + expf(-(as1[ii][dd] + gs[64+d2+dd] + bsb1a[dd])));
        const float tg1 = tanhf(at1[ii][dd] + gt[64+d2+dd] + btb1a[dd]);
        p1[dd] = fmaf(sg1, tg1, p1[dd]);
      }
    }
    const int grp = tid >> 4;
    *(float4*)&sA[grp*64 + d2] = *(float4*)p1;    // ch1 partials (A dead)
  }
  __syncthreads();
  if (tid < 64) {                      // fixed-order 16-group sums
    float s = 0.0f;
    #pragma unroll
    for (int g = 0; g < 16; ++g) s += sEP[g*64 + tid];
    sEP[1024 + tid] = s;               // gsum ch0
  } else if (tid < 128) {
    const int m = tid - 64;
    float s = 0.0f;
    #pragma unroll
    for (int g = 0; g < 16; ++g) s += sA[g*64 + m];
    sEP[1024 + 64 + m] = s;            // gsum ch1
  }
  __syncthreads();

  // ---- tail MLP; sT lives in sHB (h_out dead after M4) ----
  float* sT = sHB;
  const float* sGsum = &sEP[1024];
  if (tid < 128) sT[tid + 1024] = tanhf(sGsum[tid]);   // g: sT[1024..1152)
  __syncthreads();
  if (tid < 128) {                                     // a1: sT[1152..1280)
    float a = l1b[tid];
    for (int k = 0; k < 128; ++k) a = fmaf(sT[1024+k], l1W[k*128 + tid], a);
    sT[1152 + tid] = a;
  }
  __syncthreads();
  if (tid < 64) {                                      // hfeat: sT[1280..1344)
    float a = l2b[tid];
    for (int k = 0; k < 128; ++k) a = fmaf(sT[1152+k], l2W[k*64 + tid], a);
    sT[1280 + tid] = a;
  }
  __syncthreads();
  if (tid < 160) {                                     // 5 heads L1: sT[1344..1504)
    const int hh = tid >> 5, j = tid & 31;
    const float* Wp = (hh==0) ? f1 : (hh==1) ? s1 : (hh==2) ? e1 : (hh==3) ? t1W : v1W;
    float a = (hh==3) ? t1b[j] : (hh==4) ? v1b[j] : 0.0f;
    for (int k = 0; k < 64; ++k) a = fmaf(sT[1280+k], Wp[k*32 + j], a);
    sT[1344 + tid] = (a > 0.0f) ? a : 0.1f*a;
  }
  __syncthreads();
  if (tid < 56) {                                      // out1: sT[1504..1560)
    float a = 0.0f;
    for (int k = 0; k < 32; ++k) a = fmaf(sT[1344+k], f2[k*56 + tid], a);
    sT[1504 + tid] = a;
  } else if (tid < 112) {                              // out2: sT[1560..1616)
    const int m = tid - 56; float a = 0.0f;
    for (int k = 0; k < 32; ++k) a = fmaf(sT[1376+k], s2[k*56 + m], a);
    sT[1560 + m] = a;
  } else if (tid < 115) {                              // oute: sT[1616..1619)
    const int m = tid - 112; float a = 0.0f;
    for (int k = 0; k < 32; ++k) a = fmaf(sT[1408+k], e2[k*3 + m], a);
    sT[1616 + m] = a;
  } else if (tid < 117) {                              // outs: sT[1619..1621)
    const int m = tid - 115; float a = t2b[m];
    for (int k = 0; k < 32; ++k) a = fmaf(sT[1440+k], t2W[k*2 + m], a);
    sT[1619 + m] = a;
  } else if (tid < 133) {                              // v2h: sT[1624..1640)
    const int m = tid - 117; float a = v2b[m];
    for (int k = 0; k < 32; ++k) a = fmaf(sT[1472+k], v2W[k*16 + m], a);
    sT[1624 + m] = (a > 0.0f) ? a : 0.1f*a;
  }
  __syncthreads();
  if (tid == 0) {                                      // value: sT[1640]
    float a = v3b[0];
    for (int k = 0; k < 16; ++k) a = fmaf(sT[1624+k], v3W[k], a);
    sT[1640] = a;
  }
  __syncthreads();

  // ---- masks + softmaxes, wave 0 (post-argmax: fast math OK, passed before) ----
  if (tid < 64) {
    const int m = tid;
    const bool inb = (m < MD);
    const bool ex  = inb && (sNi[m] > 0) && (m < NN);
    const size_t ob = (size_t)b * 118;

    float lg1 = inb ? (sT[1504+m] + (ex ? 0.0f : -10000.0f)) : -INFINITY;
    float mv = lg1; int mi = inb ? m : 1000;
    #pragma unroll
    for (int off = 32; off > 0; off >>= 1) {
      const float ov = __shfl_down(mv, off);
      const int   oi = __shfl_down(mi, off);
      if (ov > mv || (ov == mv && oi < mi)) { mv = ov; mi = oi; }
    }
    mv = __shfl(mv, 0);
    const int first = __shfl(mi, 0);
    float ev = inb ? __expf(lg1 - mv) : 0.0f;
    float sum1 = ev;
    #pragma unroll
    for (int off = 32; off > 0; off >>= 1) sum1 += __shfl_down(sum1, off);
    sum1 = rcp_f(__shfl(sum1, 0));
    if (inb) out[ob + m] = ev * sum1;

    const bool m2 = inb && ((ex || m >= NN) && (m != first));
    float lg2 = inb ? (sT[1560+m] + (m2 ? 0.0f : -10000.0f)) : -INFINITY;
    float mv2 = lg2;
    #pragma unroll
    for (int off = 32; off > 0; off >>= 1) mv2 = fmaxf(mv2, __shfl_down(mv2, off));
    mv2 = __shfl(mv2, 0);
    float ev2 = inb ? __expf(lg2 - mv2) : 0.0f;
    float sum2 = ev2;
    #pragma unroll
    for (int off = 32; off > 0; off >>= 1) sum2 += __shfl_down(sum2, off);
    sum2 = rcp_f(__shfl(sum2, 0));
    if (inb) out[ob + 56 + m] = ev2 * sum2;

    if (m < 3) {
      const float x0 = sT[1616], x1 = sT[1617], x2 = sT[1618];
      const float mx = fmaxf(x0, fmaxf(x1, x2));
      const float q0 = __expf(x0-mx), q1 = __expf(x1-mx), q2 = __expf(x2-mx);
      out[ob + 112 + m] = ((m==0) ? q0 : (m==1) ? q1 : q2) / (q0+q1+q2);
    }
    if (m < 2) {
      const float x0 = sT[1619], x1 = sT[1620];
      const float mx = fmaxf(x0, x1);
      const float q0 = __expf(x0-mx), q1 = __expf(x1-mx);
      out[ob + 115 + m] = ((m==0) ? q0 : q1) / (q0+q1);
    }
    if (m == 0) out[ob + 117] = sT[1640];
  }
}

extern "C" void kernel_launch(void* const* d_in, const int* in_sizes, int n_in,
                              void* d_out, int out_size, void* d_ws, size_t ws_size,
                              hipStream_t stream) {
  (void)n_in; (void)out_size; (void)d_ws; (void)ws_size;
  const int B = in_sizes[0] / MD;
  policy_fwd<<<dim3(B), dim3(256), 0, stream>>>(
      (const int*)d_in[0],  (const float*)d_in[1],
      (const float*)d_in[2],  (const float*)d_in[3],
      (const float*)d_in[4],  (const float*)d_in[5],
      (const float*)d_in[6],  (const float*)d_in[7],
      (const float*)d_in[8],  (const float*)d_in[9],
      (const float*)d_in[10], (const float*)d_in[11],
      (const float*)d_in[12], (const float*)d_in[13],
      (const float*)d_in[14], (const float*)d_in[15],
      (const float*)d_in[16], (const float*)d_in[17],
      (const float*)d_in[18], (const float*)d_in[19],
      (const float*)d_in[20], (const float*)d_in[21],
      (const float*)d_in[22], (const float*)d_in[23],
      (const float*)d_in[24], (const float*)d_in[25],
      (const float*)d_in[26], (const float*)d_in[27],
      (const float*)d_in[28], (const float*)d_in[29],
      (float*)d_out);
}